// Round 1
// baseline (2579.946 us; speedup 1.0000x reference)
//
#include <hip/hip_runtime.h>
#include <math.h>

// ---------------------------------------------------------------------------
// GCN, 3 layers: 165 -> 32 -> 16 -> 2, log_softmax.
// Refactor: hs = dinv[n] * (in @ W). agg initialized to hs (self-loop msg),
// scatter adds hs[src] into agg[dst]. Next layer input = relu(dinv*agg + b)
// computed on the fly (epilogue fused into next GEMM). deg computed once.
// ---------------------------------------------------------------------------

__global__ __launch_bounds__(256) void deg_kernel(const int* __restrict__ dst,
                                                  float* __restrict__ deg, int E) {
    int e = blockIdx.x * blockDim.x + threadIdx.x;
    if (e < E) atomicAdd(&deg[dst[e]], 1.0f);
}

__global__ __launch_bounds__(256) void dinv_kernel(const float* __restrict__ deg,
                                                   float* __restrict__ dinv, int N) {
    int n = blockIdx.x * blockDim.x + threadIdx.x;
    if (n < N) dinv[n] = rsqrtf(deg[n] + 1.0f);
}

// FIRST=true: `in` is raw x[N,DIN].
// FIRST=false: `in` is agg_prev[N,DIN]; input feature = relu(dinv[n]*in + bprev).
template <int DIN, int DOUT, bool FIRST>
__global__ __launch_bounds__(256) void gemm_kernel(
    const float* __restrict__ in, const float* __restrict__ bprev,
    const float* __restrict__ W, const float* __restrict__ dinv,
    float* __restrict__ hs, float* __restrict__ agg, int N) {
    __shared__ float Ws[DIN * DOUT];
    __shared__ float bs[FIRST ? 1 : DIN];
    int tid = threadIdx.x;
    for (int i = tid; i < DIN * DOUT; i += 256) Ws[i] = W[i];
    if (!FIRST) {
        for (int i = tid; i < DIN; i += 256) bs[i] = bprev[i];
    }
    __syncthreads();
    int n = blockIdx.x * 256 + tid;
    if (n >= N) return;
    float dv = dinv[n];
    float acc[DOUT];
#pragma unroll
    for (int d = 0; d < DOUT; d++) acc[d] = 0.f;
    const float* row = in + (size_t)n * DIN;
    for (int k = 0; k < DIN; k++) {
        float xv;
        if (FIRST) {
            xv = row[k];
        } else {
            xv = fmaxf(fmaf(dv, row[k], bs[k]), 0.f);
        }
#pragma unroll
        for (int d = 0; d < DOUT; d++) acc[d] = fmaf(xv, Ws[k * DOUT + d], acc[d]);
    }
    float* hp = hs + (size_t)n * DOUT;
    float* ap = agg + (size_t)n * DOUT;
#pragma unroll
    for (int d = 0; d < DOUT; d++) {
        float v = dv * acc[d];
        hp[d] = v;   // message value (dinv[src] * h[src])
        ap[d] = v;   // agg initialized with self-loop message
    }
}

// DOUT divisible by 4: DOUT/4 threads per edge, each does a float4 gather and
// 4 scalar f32 atomics. Lanes covering one edge touch 128B contiguous.
template <int DOUT>
__global__ __launch_bounds__(256) void scatter_kernel(
    const float* __restrict__ hs, const int* __restrict__ src,
    const int* __restrict__ dst, float* __restrict__ agg, int E) {
    constexpr int TPE = DOUT / 4;
    int gid = blockIdx.x * blockDim.x + threadIdx.x;
    int e = gid / TPE;
    int c = gid % TPE;
    if (e >= E) return;
    int s = src[e];
    int d = dst[e];
    const float4 v = *(const float4*)(hs + (size_t)s * DOUT + c * 4);
    float* p = agg + (size_t)d * DOUT + c * 4;
    atomicAdd(p + 0, v.x);
    atomicAdd(p + 1, v.y);
    atomicAdd(p + 2, v.z);
    atomicAdd(p + 3, v.w);
}

// DOUT = 2 special case: one thread per edge.
__global__ __launch_bounds__(256) void scatter2_kernel(
    const float* __restrict__ hs, const int* __restrict__ src,
    const int* __restrict__ dst, float* __restrict__ agg, int E) {
    int e = blockIdx.x * blockDim.x + threadIdx.x;
    if (e >= E) return;
    int s = src[e];
    int d = dst[e];
    const float2 v = *(const float2*)(hs + (size_t)s * 2);
    atomicAdd(&agg[(size_t)d * 2 + 0], v.x);
    atomicAdd(&agg[(size_t)d * 2 + 1], v.y);
}

__global__ __launch_bounds__(256) void final_kernel(
    const float* __restrict__ agg, const float* __restrict__ dinv,
    const float* __restrict__ b, float* __restrict__ out, int N) {
    int n = blockIdx.x * blockDim.x + threadIdx.x;
    if (n >= N) return;
    float dv = dinv[n];
    float z0 = fmaf(dv, agg[(size_t)n * 2 + 0], b[0]);
    float z1 = fmaf(dv, agg[(size_t)n * 2 + 1], b[1]);
    float m = fmaxf(z0, z1);
    float lse = m + logf(expf(z0 - m) + expf(z1 - m));
    out[(size_t)n * 2 + 0] = z0 - lse;
    out[(size_t)n * 2 + 1] = z1 - lse;
}

extern "C" void kernel_launch(void* const* d_in, const int* in_sizes, int n_in,
                              void* d_out, int out_size, void* d_ws, size_t ws_size,
                              hipStream_t stream) {
    const float* x  = (const float*)d_in[0];
    const int*   ei = (const int*)d_in[1];
    const float* W1 = (const float*)d_in[2];
    const float* b1 = (const float*)d_in[3];
    const float* W2 = (const float*)d_in[4];
    const float* b2 = (const float*)d_in[5];
    const float* W3 = (const float*)d_in[6];
    const float* b3 = (const float*)d_in[7];
    float* out = (float*)d_out;

    const int N = in_sizes[0] / 165;  // 100000
    const int E = in_sizes[1] / 2;    // 3200000
    const int* src = ei;
    const int* dst = ei + E;

    float* ws   = (float*)d_ws;
    float* deg  = ws;  ws += N;
    float* dinv = ws;  ws += N;
    float* hs1  = ws;  ws += (size_t)N * 32;
    float* agg1 = ws;  ws += (size_t)N * 32;
    float* hs2  = ws;  ws += (size_t)N * 16;
    float* agg2 = ws;  ws += (size_t)N * 16;
    float* hs3  = ws;  ws += (size_t)N * 2;
    float* agg3 = ws;  ws += (size_t)N * 2;

    hipMemsetAsync(deg, 0, (size_t)N * sizeof(float), stream);
    deg_kernel<<<(E + 255) / 256, 256, 0, stream>>>(dst, deg, E);
    dinv_kernel<<<(N + 255) / 256, 256, 0, stream>>>(deg, dinv, N);

    // Layer 1: 165 -> 32
    gemm_kernel<165, 32, true><<<(N + 255) / 256, 256, 0, stream>>>(
        x, nullptr, W1, dinv, hs1, agg1, N);
    scatter_kernel<32><<<(E * 8 + 255) / 256, 256, 0, stream>>>(hs1, src, dst, agg1, E);

    // Layer 2: 32 -> 16 (input = relu(dinv*agg1 + b1), fused)
    gemm_kernel<32, 16, false><<<(N + 255) / 256, 256, 0, stream>>>(
        agg1, b1, W2, dinv, hs2, agg2, N);
    scatter_kernel<16><<<(E * 4 + 255) / 256, 256, 0, stream>>>(hs2, src, dst, agg2, E);

    // Layer 3: 16 -> 2 (input = relu(dinv*agg2 + b2), fused)
    gemm_kernel<16, 2, false><<<(N + 255) / 256, 256, 0, stream>>>(
        agg2, b2, W3, dinv, hs3, agg3, N);
    scatter2_kernel<<<(E + 255) / 256, 256, 0, stream>>>(hs3, src, dst, agg3, E);

    final_kernel<<<(N + 255) / 256, 256, 0, stream>>>(agg3, dinv, b3, out, N);
}

// Round 2
// 739.918 us; speedup vs baseline: 3.4868x; 3.4868x over previous
//
#include <hip/hip_runtime.h>
#include <math.h>

// ---------------------------------------------------------------------------
// GCN 165->32->16->2 + log_softmax, N=100k nodes, E=3.2M edges.
//
// Round 2: replace f32-atomic scatter (WRITE_SIZE 1.6GB, write-through
// atomics = 2ms of the 2.6ms total) with CSR build + register-accumulating
// gather. Per call: histogram(dst) -> 2-level exclusive scan -> placement
// (1 int atomic/edge) -> per-layer gather with exclusive row ownership.
// hs = dinv*(in@W); agg[n] = hs[n] + sum_{s->n} hs[s];
// next layer input = relu(dinv*agg + b) fused into next GEMM's read.
// ---------------------------------------------------------------------------

constexpr int NT = 256;

__global__ __launch_bounds__(NT) void hist_kernel(const int* __restrict__ dst,
                                                  int* __restrict__ hist, int E) {
    int e = blockIdx.x * NT + threadIdx.x;
    if (e < E) atomicAdd(&hist[dst[e]], 1);
}

// per-256-tile sums of hist
__global__ __launch_bounds__(NT) void blocksum_kernel(const int* __restrict__ hist,
                                                      int* __restrict__ bsum, int N) {
    __shared__ int s[NT];
    int i = blockIdx.x * NT + threadIdx.x;
    int v = (i < N) ? hist[i] : 0;
    s[threadIdx.x] = v;
    __syncthreads();
    for (int off = NT / 2; off > 0; off >>= 1) {
        if (threadIdx.x < off) s[threadIdx.x] += s[threadIdx.x + off];
        __syncthreads();
    }
    if (threadIdx.x == 0) bsum[blockIdx.x] = s[0];
}

// single-block exclusive scan of bsum[NB], NB <= 1024
__global__ __launch_bounds__(1024) void scanb_kernel(int* __restrict__ bsum, int NB) {
    __shared__ int s[1024];
    int t = threadIdx.x;
    int v = (t < NB) ? bsum[t] : 0;
    s[t] = v;
    __syncthreads();
    for (int off = 1; off < 1024; off <<= 1) {
        int add = (t >= off) ? s[t - off] : 0;
        __syncthreads();
        s[t] += add;
        __syncthreads();
    }
    if (t < NB) bsum[t] = s[t] - v;  // exclusive
}

// local exclusive scan per tile + tile offset -> rowptr & cursor; fused dinv
__global__ __launch_bounds__(NT) void rowptr_kernel(
    const int* __restrict__ hist, const int* __restrict__ bsum,
    int* __restrict__ rowptr, int* __restrict__ cursor,
    float* __restrict__ dinv, int N) {
    __shared__ int s[NT];
    int i = blockIdx.x * NT + threadIdx.x;
    int v = (i < N) ? hist[i] : 0;
    s[threadIdx.x] = v;
    __syncthreads();
    for (int off = 1; off < NT; off <<= 1) {
        int add = (threadIdx.x >= off) ? s[threadIdx.x - off] : 0;
        __syncthreads();
        s[threadIdx.x] += add;
        __syncthreads();
    }
    if (i < N) {
        int excl = s[threadIdx.x] - v + bsum[blockIdx.x];
        rowptr[i] = excl;
        cursor[i] = excl;
        dinv[i] = rsqrtf((float)v + 1.0f);
    }
}

__global__ __launch_bounds__(NT) void place_kernel(
    const int* __restrict__ src, const int* __restrict__ dst,
    int* __restrict__ cursor, int* __restrict__ esrc, int E) {
    int e = blockIdx.x * NT + threadIdx.x;
    if (e < E) {
        int pos = atomicAdd(&cursor[dst[e]], 1);
        esrc[pos] = src[e];
    }
}

// FIRST=true: `in` is raw x[N,DIN]; else feature = relu(dinv[n]*in + bprev).
template <int DIN, int DOUT, bool FIRST>
__global__ __launch_bounds__(NT) void gemm_kernel(
    const float* __restrict__ in, const float* __restrict__ bprev,
    const float* __restrict__ W, const float* __restrict__ dinv,
    float* __restrict__ hs, int N) {
    __shared__ float Ws[DIN * DOUT];
    __shared__ float bs[FIRST ? 1 : DIN];
    int tid = threadIdx.x;
    for (int i = tid; i < DIN * DOUT; i += NT) Ws[i] = W[i];
    if (!FIRST) {
        for (int i = tid; i < DIN; i += NT) bs[i] = bprev[i];
    }
    __syncthreads();
    int n = blockIdx.x * NT + tid;
    if (n >= N) return;
    float dv = dinv[n];
    float acc[DOUT];
#pragma unroll
    for (int d = 0; d < DOUT; d++) acc[d] = 0.f;
    const float* row = in + (size_t)n * DIN;
    for (int k = 0; k < DIN; k++) {
        float xv;
        if (FIRST) {
            xv = row[k];
        } else {
            xv = fmaxf(fmaf(dv, row[k], bs[k]), 0.f);
        }
#pragma unroll
        for (int d = 0; d < DOUT; d++) acc[d] = fmaf(xv, Ws[k * DOUT + d], acc[d]);
    }
    float* hp = hs + (size_t)n * DOUT;
#pragma unroll
    for (int d = 0; d < DOUT; d++) hp[d] = dv * acc[d];
}

// DOUT/4 lanes per node, float4 chunks; exclusive ownership, no atomics.
template <int DOUT>
__global__ __launch_bounds__(NT) void gather_kernel(
    const float* __restrict__ hs, const int* __restrict__ esrc,
    const int* __restrict__ rowptr, const int* __restrict__ hist,
    float* __restrict__ agg, int N) {
    constexpr int TPN = DOUT / 4;
    int gid = blockIdx.x * NT + threadIdx.x;
    int n = gid / TPN;
    int c = gid % TPN;
    if (n >= N) return;
    int start = rowptr[n];
    int cnt = hist[n];
    const float4* base = (const float4*)hs;
    float4 acc = base[(size_t)n * TPN + c];  // self-loop message
    for (int j = 0; j < cnt; j++) {
        int s = esrc[start + j];
        float4 v = base[(size_t)s * TPN + c];
        acc.x += v.x; acc.y += v.y; acc.z += v.z; acc.w += v.w;
    }
    ((float4*)agg)[(size_t)n * TPN + c] = acc;
}

// Layer 3 gather (DOUT=2) fused with bias + log_softmax.
__global__ __launch_bounds__(NT) void final_kernel(
    const float* __restrict__ hs3, const int* __restrict__ esrc,
    const int* __restrict__ rowptr, const int* __restrict__ hist,
    const float* __restrict__ dinv, const float* __restrict__ b,
    float* __restrict__ out, int N) {
    int n = blockIdx.x * NT + threadIdx.x;
    if (n >= N) return;
    int start = rowptr[n];
    int cnt = hist[n];
    const float2* h2 = (const float2*)hs3;
    float2 acc = h2[n];
    for (int j = 0; j < cnt; j++) {
        float2 v = h2[esrc[start + j]];
        acc.x += v.x; acc.y += v.y;
    }
    float dv = dinv[n];
    float z0 = fmaf(dv, acc.x, b[0]);
    float z1 = fmaf(dv, acc.y, b[1]);
    float m = fmaxf(z0, z1);
    float lse = m + logf(expf(z0 - m) + expf(z1 - m));
    out[(size_t)n * 2 + 0] = z0 - lse;
    out[(size_t)n * 2 + 1] = z1 - lse;
}

extern "C" void kernel_launch(void* const* d_in, const int* in_sizes, int n_in,
                              void* d_out, int out_size, void* d_ws, size_t ws_size,
                              hipStream_t stream) {
    const float* x  = (const float*)d_in[0];
    const int*   ei = (const int*)d_in[1];
    const float* W1 = (const float*)d_in[2];
    const float* b1 = (const float*)d_in[3];
    const float* W2 = (const float*)d_in[4];
    const float* b2 = (const float*)d_in[5];
    const float* W3 = (const float*)d_in[6];
    const float* b3 = (const float*)d_in[7];
    float* out = (float*)d_out;

    const int N = in_sizes[0] / 165;  // 100000
    const int E = in_sizes[1] / 2;    // 3200000
    const int* src = ei;
    const int* dst = ei + E;
    const int NB = (N + NT - 1) / NT;  // 391

    char* p = (char*)d_ws;
    int* hist   = (int*)p;   p += (size_t)N * 4;
    int* bsum   = (int*)p;   p += 1024 * 4;
    int* rowptr = (int*)p;   p += (size_t)N * 4;
    int* cursor = (int*)p;   p += (size_t)N * 4;
    int* esrc   = (int*)p;   p += (size_t)E * 4;
    float* dinv = (float*)p; p += (size_t)N * 4;
    float* hs1  = (float*)p; p += (size_t)N * 32 * 4;  // reused: hs2 (16N) + agg2 (16N)
    float* agg1 = (float*)p; p += (size_t)N * 32 * 4;
    float* hs3  = (float*)p; p += (size_t)N * 2 * 4;
    float* hs2  = hs1;           // hs1 dead after gather<32>
    float* agg2 = hs1 + (size_t)N * 16;

    hipMemsetAsync(hist, 0, (size_t)N * sizeof(int), stream);
    hist_kernel<<<(E + NT - 1) / NT, NT, 0, stream>>>(dst, hist, E);
    blocksum_kernel<<<NB, NT, 0, stream>>>(hist, bsum, N);
    scanb_kernel<<<1, 1024, 0, stream>>>(bsum, NB);
    rowptr_kernel<<<NB, NT, 0, stream>>>(hist, bsum, rowptr, cursor, dinv, N);
    place_kernel<<<(E + NT - 1) / NT, NT, 0, stream>>>(src, dst, cursor, esrc, E);

    // Layer 1: 165 -> 32
    gemm_kernel<165, 32, true><<<NB, NT, 0, stream>>>(x, nullptr, W1, dinv, hs1, N);
    gather_kernel<32><<<((size_t)N * 8 + NT - 1) / NT, NT, 0, stream>>>(
        hs1, esrc, rowptr, hist, agg1, N);

    // Layer 2: 32 -> 16
    gemm_kernel<32, 16, false><<<NB, NT, 0, stream>>>(agg1, b1, W2, dinv, hs2, N);
    gather_kernel<16><<<((size_t)N * 4 + NT - 1) / NT, NT, 0, stream>>>(
        hs2, esrc, rowptr, hist, agg2, N);

    // Layer 3: 16 -> 2, gather + bias + log_softmax fused
    gemm_kernel<16, 2, false><<<NB, NT, 0, stream>>>(agg2, b2, W3, dinv, hs3, N);
    final_kernel<<<NB, NT, 0, stream>>>(hs3, esrc, rowptr, hist, dinv, b3, out, N);
}